// Round 20
// baseline (189.318 us; speedup 1.0000x reference)
//
#include <hip/hip_runtime.h>
#include <hip/hip_cooperative_groups.h>

namespace cg = cooperative_groups;
typedef float v4f __attribute__((ext_vector_type(4)));

struct GateMem {
    float xm[3072];                 // means [t][c]
    float gs[3072];                 // gate [c*12+t]
    float part[384];
    float ybn[192], y1[192], mv[192];
};
union SMem {
    float stage[6400];              // P1: 256 rows x 25 floats (25.6 KB)
    GateMem g;                      // P2/P3 (28.4 KB)
};

// Coop grid 1024 x 256 (4 blocks/CU resident).
// P1: independent many-block row-mean streaming (R8-K1 proven shape, ~6 TB/s).
// grid.sync (R13-proven coherent for xbar).
// P2: gate chain per (n, quad, half) — redundant across halves, wsq L2-hot.
// P3: apply from L3-resident x (R13-proven: NT stores don't churn L3) + NT store.
__global__ __launch_bounds__(256, 4) void k_coop2(
    const float* __restrict__ x,
    const float* __restrict__ wsq, const float* __restrict__ bsq,
    const float* __restrict__ gamma, const float* __restrict__ beta,
    const float* __restrict__ rmean, const float* __restrict__ rvar,
    const float* __restrict__ wc1, const float* __restrict__ bc1,
    const float* __restrict__ wex, const float* __restrict__ bex,
    float* __restrict__ xbar, float* __restrict__ out)
{
    __shared__ SMem S;
    const int tid = threadIdx.x;
    const unsigned bid = blockIdx.x;

    // ================= P1: row means, 6 chunks of 256 rows =================
    {
        const v4f* x4 = (const v4f*)x;
        #pragma unroll 1
        for (int ch = 0; ch < 6; ++ch) {
            const unsigned base4 = bid * 9600u + (unsigned)ch * 1600u;
            #pragma unroll
            for (int i = 0; i < 7; ++i) {
                int j = i * 256 + tid;
                if (j < 1600) ((v4f*)S.stage)[j] = x4[base4 + j];
            }
            __syncthreads();
            const float* row = S.stage + tid * 25;
            float s = 0.f;
            #pragma unroll
            for (int v = 0; v < 25; ++v) s += row[v];    // stride 25: conflict-free
            xbar[bid * 1536u + (unsigned)ch * 256u + tid] = s * 0.04f;
            __syncthreads();
        }
    }
    cg::this_grid().sync();

    // ================= P2: gate chain for (n, quad, half) =================
    const unsigned o  = (bid & 7u) * 128u + (bid >> 3);   // bijective XCD chunk swizzle
    const unsigned n  = o >> 3;
    const unsigned qd = (o >> 1) & 3u;
    const unsigned hf = o & 1u;

    for (int j = tid; j < 3072; j += 256) {               // xbar slice -> [t][c]
        int c = j / 12, t = j - c * 12;
        S.g.xm[t * 256 + c] = xbar[(unsigned)((n * 256u + c) * 48u + qd * 12u + t)];
    }
    __syncthreads();
    for (int p = tid; p < 384; p += 256) {                // B1: squeeze partials
        int t = p >> 5, rh = p & 31, r = rh >> 1, h = rh & 1;
        const float* wrow = wsq + r * 256 + h * 128;      // L2-hot (16 KB shared)
        float acc = 0.f;
        #pragma unroll 8
        for (int i = 0; i < 128; ++i) acc += S.g.xm[t * 256 + h * 128 + i] * wrow[i];
        S.g.part[p] = acc;
    }
    __syncthreads();
    if (tid < 192) {                                      // B1b: combine + BN
        int t = tid >> 4, r = tid & 15;
        float acc = S.g.part[t * 32 + r * 2] + S.g.part[t * 32 + r * 2 + 1];
        float sc = gamma[r] * rsqrtf(rvar[r] + 1e-5f);
        S.g.ybn[t * 16 + r] = (acc + bsq[r]) * sc + (beta[r] - rmean[r] * sc);
    }
    __syncthreads();
    if (tid < 192) {                                      // B2: conv1
        int t = tid >> 4, s = tid & 15;
        float acc = bc1[s];
        #pragma unroll
        for (int r = 0; r < 16; ++r) acc += S.g.ybn[t * 16 + r] * wc1[s * 16 + r];
        S.g.y1[t * 16 + s] = acc;
    }
    __syncthreads();
    if (tid < 192) {                                      // B3: temporal diff
        int t = tid >> 4;
        S.g.mv[tid] = ((t % 3) < 2) ? (S.g.y1[tid + 16] - S.g.ybn[tid]) : 0.f;
    }
    __syncthreads();
    {                                                     // B4: expand + sigmoid
        int c = tid;
        float wexr[16];
        #pragma unroll
        for (int r = 0; r < 16; ++r) wexr[r] = wex[c * 16 + r];
        float be = bex[c];
        #pragma unroll
        for (int t = 0; t < 12; ++t) {
            float a = be;
            #pragma unroll
            for (int r = 0; r < 16; ++r) a += S.g.mv[t * 16 + r] * wexr[r];
            S.g.gs[c * 12 + t] = 1.f / (1.f + expf(-a));
        }
    }
    __syncthreads();

    // ================= P3: apply 128 channels of the quad =================
    {
        const v4f* x4g = (const v4f*)x + (size_t)n * 76800u + qd * 75u;  // + cc*300 + k
        v4f*       o4g = (v4f*)out     + (size_t)n * 76800u + qd * 75u;
        #pragma unroll 4
        for (int it = 0; it < 38; ++it) {
            int j = it * 256 + tid;                       // 0..9727, use <9600
            if (j < 9600) {
                unsigned cl = ((unsigned)j * 55926u) >> 22;   // j/75 (exact j<19200)
                int k = j - (int)cl * 75;
                unsigned cc = hf * 128u + cl;
                v4f v = x4g[cc * 300u + (unsigned)k];
                int m0  = k * 4;
                int t0  = (m0 * 41) >> 10;                // m0/25 (exact m0<1024)
                int t3  = ((m0 + 3) * 41) >> 10;
                int rem = m0 - t0 * 25;
                float g0 = S.g.gs[cc * 12u + (unsigned)t0];
                float g3 = S.g.gs[cc * 12u + (unsigned)t3];
                v4f ov;
                ov.x = v.x * g0;
                ov.y = v.y * ((rem + 1 < 25) ? g0 : g3);
                ov.z = v.z * ((rem + 2 < 25) ? g0 : g3);
                ov.w = v.w * ((rem + 3 < 25) ? g0 : g3);
                __builtin_nontemporal_store(ov, &o4g[cc * 300u + (unsigned)k]);
            }
        }
    }
}

extern "C" void kernel_launch(void* const* d_in, const int* in_sizes, int n_in,
                              void* d_out, int out_size, void* d_ws, size_t ws_size,
                              hipStream_t stream) {
    const float* x     = (const float*)d_in[0];
    const float* wsq   = (const float*)d_in[1];
    const float* bsq   = (const float*)d_in[2];
    const float* gamma = (const float*)d_in[3];
    const float* beta  = (const float*)d_in[4];
    const float* rmean = (const float*)d_in[5];
    const float* rvar  = (const float*)d_in[6];
    const float* wc1   = (const float*)d_in[7];
    const float* bc1   = (const float*)d_in[8];
    const float* wex   = (const float*)d_in[9];
    const float* bex   = (const float*)d_in[10];
    float* xbar = (float*)d_ws;                    // N*C*T floats = 6.29 MB
    float* outp = (float*)d_out;

    void* args[] = { (void*)&x, (void*)&wsq, (void*)&bsq, (void*)&gamma,
                     (void*)&beta, (void*)&rmean, (void*)&rvar, (void*)&wc1,
                     (void*)&bc1, (void*)&wex, (void*)&bex,
                     (void*)&xbar, (void*)&outp };
    hipLaunchCooperativeKernel((const void*)k_coop2, dim3(1024), dim3(256),
                               args, 0, stream);
}

// Round 21
// 79.492 us; speedup vs baseline: 2.3816x; 2.3816x over previous
//
#include <hip/hip_runtime.h>

typedef float v4f __attribute__((ext_vector_type(4)));

// R19 skeleton with a BARRIER-FREE wave-independent read phase:
//   8 waves x 32 channels each; 16 rounds of 2 channels through a wave-private
//   double-buffered LDS slot. No __syncthreads until the read phase ends ->
//   16 independently-timed wave streams per CU (the R8-K1 many-small-block
//   regime, measured ~6 TB/s). B1 squeeze moved to epilogue (all 512 threads).
//   wsqL + gs alias the wave buffers after the read phase. Apply = R19 verbatim.
__global__ __launch_bounds__(512, 4) void k_fused11(
    const float* __restrict__ x,
    const float* __restrict__ wsq, const float* __restrict__ bsq,
    const float* __restrict__ gamma, const float* __restrict__ beta,
    const float* __restrict__ rmean, const float* __restrict__ rvar,
    const float* __restrict__ wc1, const float* __restrict__ bc1,
    const float* __restrict__ wex, const float* __restrict__ bex,
    float* __restrict__ out)
{
    __shared__ v4f   wb[8][2][152];    // per-wave dbuf: 150 v4f used (+2 pad) = 38,912 B
    __shared__ float xb[12 * 260];     // frame sums [t][c], stride 260        12,480 B
    __shared__ float part[384];
    __shared__ float ybn[192], y1[192], mv[192];

    float* wsqL = (float*)wb;          // [c][r] stride 17: 17,408 B (alias, post-read)
    float* gs   = (float*)wb + 4352;   // gate [c*12+t]:    12,288 B (alias, post-read)

    const int tid = threadIdx.x;
    const int w   = tid >> 6;          // wave 0..7
    const int ln  = tid & 63;
    const unsigned bid = blockIdx.x;
    const unsigned o = (bid & 7u) * 64u + (bid >> 3);   // bijective XCD chunk swizzle
    const unsigned n = o >> 2;
    const unsigned q = o & 3u;

    const v4f* x4 = (const v4f*)x + (size_t)n * 76800u + q * 75u;   // + c*300 + k
    v4f*       o4 = (v4f*)out     + (size_t)n * 76800u + q * 75u;

    const int crBase = w * 32;         // this wave's channel range

    v4f sA[3], sB[3];
    auto issueW = [&](int rnd, v4f* st) {          // 2 channels = 150 f4
        int cr = crBase + rnd * 2;
        #pragma unroll
        for (int qq = 0; qq < 3; ++qq) {
            int s = qq * 64 + ln;
            if (s < 150) {
                int c = cr + (s >= 75 ? 1 : 0);
                int k = (s >= 75) ? s - 75 : s;
                st[qq] = x4[c * 300 + k];
            }
        }
    };
    auto writeW = [&](int rnd, const v4f* st) {    // regs -> wave-private LDS
        v4f* dst = wb[w][rnd & 1];
        #pragma unroll
        for (int qq = 0; qq < 3; ++qq) {
            int s = qq * 64 + ln;
            if (s < 150) dst[s] = st[qq];
        }
    };
    auto reduceW = [&](int rnd) {                  // lanes 0..23: 2ch x 12t sums
        if (ln < 24) {
            int co = ln / 12, t = ln - co * 12;
            const float* bp = (const float*)wb[w][rnd & 1] + co * 300 + t * 25;
            float s = 0.f;
            #pragma unroll
            for (int v = 0; v < 25; ++v) s += bp[v];
            xb[t * 260 + crBase + rnd * 2 + co] = s;    // raw sum (0.04 folded in BN)
        }
    };

    // ---- read phase: 16 rounds, zero block barriers ----
    issueW(0, sA);
    issueW(1, sB);
    #pragma unroll
    for (int r = 0; r < 16; r += 2) {
        writeW(r, sA);                 // waits vmcnt for sA (issued ~2 rounds ago)
        if (r + 2 < 16) issueW(r + 2, sA);
        reduceW(r);
        writeW(r + 1, sB);
        if (r + 3 < 16) issueW(r + 3, sB);
        reduceW(r + 1);
    }
    __syncthreads();                   // single barrier: xb complete, wb dead

    // ---- wsq -> LDS transposed (L2-hot; aliases wb) ----
    #pragma unroll
    for (int it = 0; it < 8; ++it) {
        int j = it * 512 + tid;        // j = r*256 + c
        wsqL[(j & 255) * 17 + (j >> 8)] = wsq[j];
    }
    __syncthreads();

    // ---- B1: squeeze partials (t, r, half): 128 MACs each ----
    if (tid < 384) {
        int t = tid >> 5, rh = tid & 31, r = rh >> 1, hh = rh & 1;
        float acc = 0.f;
        #pragma unroll 8
        for (int i = 0; i < 128; ++i)
            acc += xb[t * 260 + hh * 128 + i] * wsqL[(hh * 128 + i) * 17 + r];
        part[tid] = acc;
    }
    __syncthreads();
    if (tid < 192) {                   // combine + BN (0.04, bsq folded)
        int t = tid >> 4, r = tid & 15;
        float acc = part[t * 32 + r * 2] + part[t * 32 + r * 2 + 1];
        float sc = gamma[r] * rsqrtf(rvar[r] + 1e-5f);
        ybn[tid] = acc * (0.04f * sc) + (bsq[r] * sc + beta[r] - rmean[r] * sc);
    }
    __syncthreads();
    if (tid < 192) {                   // conv1
        int t = tid >> 4, s = tid & 15;
        float a = bc1[s];
        #pragma unroll
        for (int r = 0; r < 16; ++r) a += ybn[t * 16 + r] * wc1[s * 16 + r];
        y1[tid] = a;
    }
    __syncthreads();
    if (tid < 192) {                   // temporal diff (quad = 4 whole segments)
        int t = tid >> 4;
        mv[tid] = ((t % 3) < 2) ? (y1[tid + 16] - ybn[tid]) : 0.f;
    }
    __syncthreads();
    {                                  // expand + sigmoid (c, t-half)
        int c = tid & 255, half = tid >> 8;
        float wexr[16];
        #pragma unroll
        for (int r = 0; r < 16; ++r) wexr[r] = wex[c * 16 + r];
        float be = bex[c];
        #pragma unroll
        for (int t = half * 6; t < half * 6 + 6; ++t) {
            float a = be;
            #pragma unroll
            for (int r = 0; r < 16; ++r) a += mv[t * 16 + r] * wexr[r];
            gs[c * 12 + t] = 1.f / (1.f + expf(-a));
        }
    }
    __syncthreads();

    // ---- apply: re-read x (L3-hot, 3x-proven), gate, NT store (R19 verbatim) ----
    #pragma unroll 4
    for (int it = 0; it < 38; ++it) {
        int j = it * 512 + tid;
        if (j < 19200) {
            unsigned c = ((unsigned)j * 55926u) >> 22;   // j/75 (exact j<19200)
            int k = j - (int)c * 75;
            v4f v = x4[c * 300 + k];
            int m0  = k * 4;
            int t0  = (m0 * 41) >> 10;                   // m0/25 (exact m0<1024)
            int t3  = ((m0 + 3) * 41) >> 10;
            int rem = m0 - t0 * 25;
            float g0 = gs[c * 12 + t0];
            float g3 = gs[c * 12 + t3];
            v4f ov;
            ov.x = v.x * g0;
            ov.y = v.y * ((rem + 1 < 25) ? g0 : g3);
            ov.z = v.z * ((rem + 2 < 25) ? g0 : g3);
            ov.w = v.w * ((rem + 3 < 25) ? g0 : g3);
            __builtin_nontemporal_store(ov, &o4[c * 300 + k]);
        }
    }
}

extern "C" void kernel_launch(void* const* d_in, const int* in_sizes, int n_in,
                              void* d_out, int out_size, void* d_ws, size_t ws_size,
                              hipStream_t stream) {
    const float* x     = (const float*)d_in[0];
    const float* wsq   = (const float*)d_in[1];
    const float* bsq   = (const float*)d_in[2];
    const float* gamma = (const float*)d_in[3];
    const float* beta  = (const float*)d_in[4];
    const float* rmean = (const float*)d_in[5];
    const float* rvar  = (const float*)d_in[6];
    const float* wc1   = (const float*)d_in[7];
    const float* bc1   = (const float*)d_in[8];
    const float* wex   = (const float*)d_in[9];
    const float* bex   = (const float*)d_in[10];

    k_fused11<<<512, 512, 0, stream>>>(x, wsq, bsq, gamma, beta,
                                       rmean, rvar, wc1, bc1, wex, bex,
                                       (float*)d_out);
}